// Round 5
// baseline (108.999 us; speedup 1.0000x reference)
//
#include <hip/hip_runtime.h>

// Problem: B=16384, X_DIM=1024, K=64, fp32 in/out.
// out[b] = 0.5 * ( sum_k (x_b . V[:,k])^2  -  sum_i x_bi^2 * w_i ),  w_i = sum_k V[i][k]^2
//
// R5: bottleneck identified as V-fragment re-fetch (256 MB) + wf (64 MB) L2 traffic.
//  - wave reuses each loaded vh/vl across 2 row-strips (32 rows) -> B traffic 128 MB
//  - compact w[1024] staged in LDS per block (broadcast reads) -> wf traffic gone
//  - x read direct from global in A-fragment pattern (L3-warm)
//  - 512 blocks x 256 thr, launch_bounds(256,4) -> 16 waves/CU wave-granular

typedef short short8 __attribute__((ext_vector_type(8)));   // 8 bf16 = 4 VGPRs
typedef float f32x4 __attribute__((ext_vector_type(4)));

constexpr int XD = 1024;
constexpr int KD = 64;

static __device__ __forceinline__ unsigned short f2bf(float f) {
    union { float f; unsigned u; } v; v.f = f;
    unsigned r = v.u + 0x7FFFu + ((v.u >> 16) & 1u);   // RNE
    return (unsigned short)(r >> 16);
}
static __device__ __forceinline__ float bf2f(unsigned short h) {
    union { unsigned u; float f; } v; v.u = ((unsigned)h) << 16;
    return v.f;
}

// ---- prep: split V into bf16 hi/lo in B-fragment order; compact w[1024] ----
// B-fragment layout (mfma_f32_16x16x32_bf16): lane l holds B[k=(l>>4)*8+j][n=l&15]
// ws layout (bytes):
//   bh @ 0      : [it:32][t:4][lane:64][j:8] bf16   (131072 B)
//   bl @ 131072 : same                               (131072 B)
//   wc @ 262144 : [i:1024] fp32 compact              (  4096 B)
__global__ void prep_kernel(const float* __restrict__ v,
                            unsigned short* __restrict__ bh,
                            unsigned short* __restrict__ bl,
                            float* __restrict__ wc) {
    int idx = blockIdx.x * 256 + threadIdx.x;   // 0..8191
    int it = idx >> 8;
    int r  = idx & 255;
    int t  = r >> 6;
    int l  = r & 63;
    int q  = l >> 4, m = l & 15;
    int base_i = it * 32 + q * 8;
    int n = t * 16 + m;
    size_t fo = ((size_t)(it * 4 + t) * 64 + l) * 8;
#pragma unroll
    for (int j = 0; j < 8; ++j) {
        float val = v[(size_t)(base_i + j) * KD + n];
        unsigned short h = f2bf(val);
        bh[fo + j] = h;
        bl[fo + j] = f2bf(val - bf2f(h));
    }
    if (t == 0 && m == 0) {   // 4 lanes (q=0..3) x 8 j cover this it's 32 i's
#pragma unroll
        for (int j = 0; j < 8; ++j) {
            const f32x4* vp = (const f32x4*)(v + (size_t)(base_i + j) * KD);
            float s = 0.f;
#pragma unroll
            for (int qq = 0; qq < KD / 4; ++qq) {
                f32x4 tv = vp[qq];
                s = fmaf(tv.x, tv.x, s); s = fmaf(tv.y, tv.y, s);
                s = fmaf(tv.z, tv.z, s); s = fmaf(tv.w, tv.w, s);
            }
            wc[base_i + j] = s;
        }
    }
}

// ---- main: block = 32 rows (2 strips); 4 waves x 8 i-tiles; V reused x2 ----
__global__ __launch_bounds__(256, 4)
void cross_r5(const float* __restrict__ x,
              const unsigned short* __restrict__ bh,
              const unsigned short* __restrict__ bl,
              const float* __restrict__ wc,
              float* __restrict__ out) {
    __shared__ float wlds[XD];                 //  4096 B
    __shared__ float comb[3][2][64][17];       // 26112 B, pitch 17 -> conflict-free
    __shared__ float zb[3][2][16];             //   384 B

    const int tid = threadIdx.x;
    const int l = tid & 63;
    const int w = tid >> 6;            // wave 0..3
    const int q = l >> 4, m = l & 15;
    const int row0 = blockIdx.x * 32;

    // stage compact w into LDS (256 thr x 4 floats, coalesced + aligned)
    {
        f32x4 v4 = *(const f32x4*)(wc + tid * 4);
        *(f32x4*)&wlds[tid * 4] = v4;
    }
    __syncthreads();

    f32x4 c[2][4];
#pragma unroll
    for (int s = 0; s < 2; ++s)
#pragma unroll
        for (int t = 0; t < 4; ++t) c[s][t] = f32x4{0.f, 0.f, 0.f, 0.f};
    float z[2] = {0.f, 0.f};

    const short8* bhp = (const short8*)bh;
    const short8* blp = (const short8*)bl;

#pragma unroll 2
    for (int ii = 0; ii < 8; ++ii) {
        const int it = w * 8 + ii;
        const size_t fbase = (size_t)(it * 4) * 64 + l;

        // load V fragments ONCE for this i-tile (reused across both strips)
        short8 vh[4], vl[4];
#pragma unroll
        for (int t = 0; t < 4; ++t) {
            vh[t] = bhp[fbase + (size_t)t * 64];
            vl[t] = blp[fbase + (size_t)t * 64];
        }

        // w broadcast reads from LDS (same addr across the 16 m-lanes -> free)
        const float* wp = &wlds[it * 32 + q * 8];
        f32x4 wa = *(const f32x4*)wp;
        f32x4 wb = *(const f32x4*)(wp + 4);

#pragma unroll
        for (int s = 0; s < 2; ++s) {
            const float* xp = x + (size_t)(row0 + s * 16 + m) * XD + it * 32 + q * 8;
            f32x4 xa = ((const f32x4*)xp)[0];
            f32x4 xb = ((const f32x4*)xp)[1];

            z[s] = fmaf(xa.x * xa.x, wa.x, z[s]); z[s] = fmaf(xa.y * xa.y, wa.y, z[s]);
            z[s] = fmaf(xa.z * xa.z, wa.z, z[s]); z[s] = fmaf(xa.w * xa.w, wa.w, z[s]);
            z[s] = fmaf(xb.x * xb.x, wb.x, z[s]); z[s] = fmaf(xb.y * xb.y, wb.y, z[s]);
            z[s] = fmaf(xb.z * xb.z, wb.z, z[s]); z[s] = fmaf(xb.w * xb.w, wb.w, z[s]);

            short8 ah, al_;
            float xs[8] = {xa.x, xa.y, xa.z, xa.w, xb.x, xb.y, xb.z, xb.w};
#pragma unroll
            for (int j = 0; j < 8; ++j) {
                unsigned short h = f2bf(xs[j]);
                ah[j] = (short)h;
                al_[j] = (short)f2bf(xs[j] - bf2f(h));
            }

#pragma unroll
            for (int t = 0; t < 4; ++t) {
                c[s][t] = __builtin_amdgcn_mfma_f32_16x16x32_bf16(ah,  vh[t], c[s][t], 0, 0, 0);
                c[s][t] = __builtin_amdgcn_mfma_f32_16x16x32_bf16(ah,  vl[t], c[s][t], 0, 0, 0);
                c[s][t] = __builtin_amdgcn_mfma_f32_16x16x32_bf16(al_, vh[t], c[s][t], 0, 0, 0);
            }
        }
    }

    // z: sum over q-chunks -> full-q partial z per (strip, row m) for this i-range
#pragma unroll
    for (int s = 0; s < 2; ++s) {
        z[s] += __shfl_xor(z[s], 16);
        z[s] += __shfl_xor(z[s], 32);
    }

    // combine partial y across the 4 waves (sum BEFORE squaring)
    if (w > 0) {
        const int slot = w - 1;
#pragma unroll
        for (int s = 0; s < 2; ++s)
#pragma unroll
            for (int t = 0; t < 4; ++t)
#pragma unroll
                for (int r = 0; r < 4; ++r) comb[slot][s][l][t * 4 + r] = c[s][t][r];
        if (l < 16) { zb[slot][0][l] = z[0]; zb[slot][1][l] = z[1]; }
    }
    __syncthreads();

    if (w == 0) {
#pragma unroll
        for (int slot = 0; slot < 3; ++slot) {
#pragma unroll
            for (int s = 0; s < 2; ++s)
#pragma unroll
                for (int t = 0; t < 4; ++t)
#pragma unroll
                    for (int r = 0; r < 4; ++r) c[s][t][r] += comb[slot][s][l][t * 4 + r];
            z[0] += zb[slot][0][m];
            z[1] += zb[slot][1][m];
        }

#pragma unroll
        for (int s = 0; s < 2; ++s) {
            // C layout: col = l&15, row = q*4 + reg
            float p[4] = {0.f, 0.f, 0.f, 0.f};
#pragma unroll
            for (int r = 0; r < 4; ++r)
#pragma unroll
                for (int t = 0; t < 4; ++t) p[r] = fmaf(c[s][t][r], c[s][t][r], p[r]);
#pragma unroll
            for (int mask = 1; mask < 16; mask <<= 1)
#pragma unroll
                for (int r = 0; r < 4; ++r) p[r] += __shfl_xor(p[r], mask);

            float zrow = __shfl(z[s], q * 4 + m, 16);
            if (m < 4) out[row0 + s * 16 + q * 4 + m] = 0.5f * (p[m] - zrow);
        }
    }
}

extern "C" void kernel_launch(void* const* d_in, const int* in_sizes, int n_in,
                              void* d_out, int out_size, void* d_ws, size_t ws_size,
                              hipStream_t stream) {
    const float* x = (const float*)d_in[0];      // (16384, 1024) fp32
    const float* v = (const float*)d_in[1];      // (1024, 64) fp32
    float* out = (float*)d_out;                  // (16384, 1) fp32

    unsigned short* bh = (unsigned short*)d_ws;                    // 131072 B
    unsigned short* bl = (unsigned short*)((char*)d_ws + 131072);  // 131072 B
    float* wc = (float*)((char*)d_ws + 262144);                    //   4096 B

    const int B = in_sizes[0] / XD;              // 16384

    hipLaunchKernelGGL(prep_kernel, dim3(32), dim3(256), 0, stream, v, bh, bl, wc);
    hipLaunchKernelGGL(cross_r5, dim3(B / 32), dim3(256), 0, stream,
                       x, bh, bl, wc, out);
}

// Round 6
// 106.783 us; speedup vs baseline: 1.0208x; 1.0208x over previous
//
#include <hip/hip_runtime.h>

// Problem: B=16384, X_DIM=1024, K=64, fp32 in/out.
// out[b] = 0.5 * ( sum_k (x_b . V[:,k])^2  -  sum_i x_bi^2 * w_i ),  w_i = sum_k V[i][k]^2
//
// R6: found prep_kernel's w-computation was a serial 128-load latency chain on
// 8 lanes/block x 32 blocks (~10-20us/iter, every iter since ws is re-poisoned).
// Fixed: w computed by 1024 parallel threads (16 independent loads each), fused
// into the same prep dispatch. Cross = R3 shape (1024 blk x 4 waves, 3 acc sets)
// + LDS-broadcast w + manually hoisted x loads per 2-tile group.

typedef short short8 __attribute__((ext_vector_type(8)));   // 8 bf16 = 4 VGPRs
typedef float f32x4 __attribute__((ext_vector_type(4)));

constexpr int XD = 1024;
constexpr int KD = 64;

static __device__ __forceinline__ unsigned short f2bf(float f) {
    union { float f; unsigned u; } v; v.f = f;
    unsigned r = v.u + 0x7FFFu + ((v.u >> 16) & 1u);   // RNE
    return (unsigned short)(r >> 16);
}
static __device__ __forceinline__ float bf2f(unsigned short h) {
    union { unsigned u; float f; } v; v.u = ((unsigned)h) << 16;
    return v.f;
}

// ---- prep: blocks 0..31 build bf16 hi/lo B-fragments; blocks 32..35 build w ----
// B-fragment layout (mfma_f32_16x16x32_bf16): lane l holds B[k=(l>>4)*8+j][n=l&15]
// ws layout (bytes):
//   bh @ 0      : [it:32][t:4][lane:64][j:8] bf16   (131072 B)
//   bl @ 131072 : same                               (131072 B)
//   wc @ 262144 : [i:1024] fp32 compact              (  4096 B)
__global__ void prep_kernel(const float* __restrict__ v,
                            unsigned short* __restrict__ bh,
                            unsigned short* __restrict__ bl,
                            float* __restrict__ wc) {
    if (blockIdx.x < 32) {
        int idx = blockIdx.x * 256 + threadIdx.x;   // 0..8191
        int it = idx >> 8;
        int r  = idx & 255;
        int t  = r >> 6;
        int l  = r & 63;
        int q  = l >> 4, m = l & 15;
        int base_i = it * 32 + q * 8;
        int n = t * 16 + m;
        size_t fo = ((size_t)(it * 4 + t) * 64 + l) * 8;
#pragma unroll
        for (int j = 0; j < 8; ++j) {
            float val = v[(size_t)(base_i + j) * KD + n];
            unsigned short h = f2bf(val);
            bh[fo + j] = h;
            bl[fo + j] = f2bf(val - bf2f(h));
        }
    } else {
        int i = (blockIdx.x - 32) * 256 + threadIdx.x;   // 0..1023
        const f32x4* vp = (const f32x4*)(v + (size_t)i * KD);
        // 16 independent loads, fully unrolled -> all in flight at once
        f32x4 tv[16];
#pragma unroll
        for (int qq = 0; qq < 16; ++qq) tv[qq] = vp[qq];
        float s = 0.f;
#pragma unroll
        for (int qq = 0; qq < 16; ++qq) {
            s = fmaf(tv[qq].x, tv[qq].x, s); s = fmaf(tv[qq].y, tv[qq].y, s);
            s = fmaf(tv[qq].z, tv[qq].z, s); s = fmaf(tv[qq].w, tv[qq].w, s);
        }
        wc[i] = s;
    }
}

// ---- main: block = 16 rows; 4 waves = i-quarters (8 tiles each); hoisted loads ----
__global__ __launch_bounds__(256, 4)
void cross_r6(const float* __restrict__ x,
              const unsigned short* __restrict__ bh,
              const unsigned short* __restrict__ bl,
              const float* __restrict__ wc,
              float* __restrict__ out) {
    __shared__ float wlds[XD];             //  4096 B
    __shared__ float comb[3][64][17];      // 13056 B, pitch 17 -> conflict-free
    __shared__ float zb[3][16];

    const int tid = threadIdx.x;
    const int l = tid & 63;
    const int w = tid >> 6;            // wave 0..3 = i-quarter
    const int q = l >> 4, m = l & 15;
    const int row0 = blockIdx.x * 16;

    // stage compact w into LDS (256 thr x f32x4, coalesced + 16B aligned)
    *(f32x4*)&wlds[tid * 4] = *(const f32x4*)(wc + tid * 4);
    __syncthreads();

    f32x4 ch[4], cl1[4], cl2[4];
#pragma unroll
    for (int t = 0; t < 4; ++t) {
        ch[t]  = f32x4{0.f, 0.f, 0.f, 0.f};
        cl1[t] = f32x4{0.f, 0.f, 0.f, 0.f};
        cl2[t] = f32x4{0.f, 0.f, 0.f, 0.f};
    }
    float z = 0.f;

    const short8* bhp = (const short8*)bh;
    const short8* blp = (const short8*)bl;
    const float* xrow = x + (size_t)(row0 + m) * XD + q * 8;

    for (int ii = 0; ii < 8; ii += 2) {
        const int it0 = w * 8 + ii;
        const int it1 = it0 + 1;

        // ---- hoist: issue ALL loads for both tiles before any consumption ----
        f32x4 xa0 = *(const f32x4*)(xrow + it0 * 32);
        f32x4 xb0 = *(const f32x4*)(xrow + it0 * 32 + 4);
        f32x4 xa1 = *(const f32x4*)(xrow + it1 * 32);
        f32x4 xb1 = *(const f32x4*)(xrow + it1 * 32 + 4);
        const size_t fb0 = (size_t)(it0 * 4) * 64 + l;
        const size_t fb1 = (size_t)(it1 * 4) * 64 + l;
        short8 vh0[4], vl0[4], vh1[4], vl1[4];
#pragma unroll
        for (int t = 0; t < 4; ++t) {
            vh0[t] = bhp[fb0 + (size_t)t * 64];
            vl0[t] = blp[fb0 + (size_t)t * 64];
        }

        // ---- tile 0 ----
        {
            const float* wp = &wlds[it0 * 32 + q * 8];
            f32x4 wa = *(const f32x4*)wp, wb = *(const f32x4*)(wp + 4);
            float xs[8] = {xa0.x, xa0.y, xa0.z, xa0.w, xb0.x, xb0.y, xb0.z, xb0.w};
            z = fmaf(xs[0]*xs[0], wa.x, z); z = fmaf(xs[1]*xs[1], wa.y, z);
            z = fmaf(xs[2]*xs[2], wa.z, z); z = fmaf(xs[3]*xs[3], wa.w, z);
            z = fmaf(xs[4]*xs[4], wb.x, z); z = fmaf(xs[5]*xs[5], wb.y, z);
            z = fmaf(xs[6]*xs[6], wb.z, z); z = fmaf(xs[7]*xs[7], wb.w, z);
            short8 ah, al_;
#pragma unroll
            for (int j = 0; j < 8; ++j) {
                unsigned short h = f2bf(xs[j]);
                ah[j] = (short)h;
                al_[j] = (short)f2bf(xs[j] - bf2f(h));
            }
            // prefetch tile 1 frags before tile-0 MFMAs
#pragma unroll
            for (int t = 0; t < 4; ++t) {
                vh1[t] = bhp[fb1 + (size_t)t * 64];
                vl1[t] = blp[fb1 + (size_t)t * 64];
            }
#pragma unroll
            for (int t = 0; t < 4; ++t) {
                ch[t]  = __builtin_amdgcn_mfma_f32_16x16x32_bf16(ah,  vh0[t], ch[t],  0, 0, 0);
                cl1[t] = __builtin_amdgcn_mfma_f32_16x16x32_bf16(ah,  vl0[t], cl1[t], 0, 0, 0);
                cl2[t] = __builtin_amdgcn_mfma_f32_16x16x32_bf16(al_, vh0[t], cl2[t], 0, 0, 0);
            }
        }
        // ---- tile 1 ----
        {
            const float* wp = &wlds[it1 * 32 + q * 8];
            f32x4 wa = *(const f32x4*)wp, wb = *(const f32x4*)(wp + 4);
            float xs[8] = {xa1.x, xa1.y, xa1.z, xa1.w, xb1.x, xb1.y, xb1.z, xb1.w};
            z = fmaf(xs[0]*xs[0], wa.x, z); z = fmaf(xs[1]*xs[1], wa.y, z);
            z = fmaf(xs[2]*xs[2], wa.z, z); z = fmaf(xs[3]*xs[3], wa.w, z);
            z = fmaf(xs[4]*xs[4], wb.x, z); z = fmaf(xs[5]*xs[5], wb.y, z);
            z = fmaf(xs[6]*xs[6], wb.z, z); z = fmaf(xs[7]*xs[7], wb.w, z);
            short8 ah, al_;
#pragma unroll
            for (int j = 0; j < 8; ++j) {
                unsigned short h = f2bf(xs[j]);
                ah[j] = (short)h;
                al_[j] = (short)f2bf(xs[j] - bf2f(h));
            }
#pragma unroll
            for (int t = 0; t < 4; ++t) {
                ch[t]  = __builtin_amdgcn_mfma_f32_16x16x32_bf16(ah,  vh1[t], ch[t],  0, 0, 0);
                cl1[t] = __builtin_amdgcn_mfma_f32_16x16x32_bf16(ah,  vl1[t], cl1[t], 0, 0, 0);
                cl2[t] = __builtin_amdgcn_mfma_f32_16x16x32_bf16(al_, vh1[t], cl2[t], 0, 0, 0);
            }
        }
    }

    // merge the 3 products (exact fp32 adds)
    f32x4 cs[4];
#pragma unroll
    for (int t = 0; t < 4; ++t) cs[t] = ch[t] + cl1[t] + cl2[t];

    // z: sum over q-chunks -> full-q partial z for row m (this i-quarter)
    z += __shfl_xor(z, 16);
    z += __shfl_xor(z, 32);

    // combine partial y across the 4 waves (sum BEFORE squaring)
    if (w > 0) {
        const int s = w - 1;
#pragma unroll
        for (int t = 0; t < 4; ++t)
#pragma unroll
            for (int r = 0; r < 4; ++r) comb[s][l][t * 4 + r] = cs[t][r];
        if (l < 16) zb[s][l] = z;
    }
    __syncthreads();

    if (w == 0) {
#pragma unroll
        for (int s = 0; s < 3; ++s) {
#pragma unroll
            for (int t = 0; t < 4; ++t)
#pragma unroll
                for (int r = 0; r < 4; ++r) cs[t][r] += comb[s][l][t * 4 + r];
            z += zb[s][m];
        }

        // C layout: col = l&15, row = q*4 + reg. p[reg] = sum over all 64 cols of y^2
        float p[4] = {0.f, 0.f, 0.f, 0.f};
#pragma unroll
        for (int r = 0; r < 4; ++r)
#pragma unroll
            for (int t = 0; t < 4; ++t) p[r] = fmaf(cs[t][r], cs[t][r], p[r]);
#pragma unroll
        for (int mask = 1; mask < 16; mask <<= 1)
#pragma unroll
            for (int r = 0; r < 4; ++r) p[r] += __shfl_xor(p[r], mask);

        // z for row (q*4 + m) lives in the lane whose m-part equals q*4+m
        float zrow = __shfl(z, q * 4 + m, 16);
        if (m < 4) out[row0 + q * 4 + m] = 0.5f * (p[m] - zrow);
    }
}

extern "C" void kernel_launch(void* const* d_in, const int* in_sizes, int n_in,
                              void* d_out, int out_size, void* d_ws, size_t ws_size,
                              hipStream_t stream) {
    const float* x = (const float*)d_in[0];      // (16384, 1024) fp32
    const float* v = (const float*)d_in[1];      // (1024, 64) fp32
    float* out = (float*)d_out;                  // (16384, 1) fp32

    unsigned short* bh = (unsigned short*)d_ws;                    // 131072 B
    unsigned short* bl = (unsigned short*)((char*)d_ws + 131072);  // 131072 B
    float* wc = (float*)((char*)d_ws + 262144);                    //   4096 B

    const int B = in_sizes[0] / XD;              // 16384

    hipLaunchKernelGGL(prep_kernel, dim3(36), dim3(256), 0, stream, v, bh, bl, wc);
    hipLaunchKernelGGL(cross_r6, dim3(B / 16), dim3(256), 0, stream,
                       x, bh, bl, wc, out);
}

// Round 7
// 102.835 us; speedup vs baseline: 1.0599x; 1.0384x over previous
//
#include <hip/hip_runtime.h>

// Problem: B=16384, X_DIM=1024, K=64, fp32 in/out.
// out[b] = 0.5 * ( sum_k (x_b . V[:,k])^2  -  sum_i x_bi^2 * w_i ),  w_i = sum_k V[i][k]^2
//
// R7: test the "linear x streaming" hypothesis PROPERLY (R4's attempt was void:
// PITCH=1025 de-aligned float4 LDS stores -> 1.5M bank conflicts).
//  - block = 16 full rows (64 KB contiguous global), staged via 8 hoisted
//    float4 loads/thread into LDS with float4-granularity XOR swizzle
//    (c' = c ^ (r&7)): 16B-aligned, bank-even on BOTH store and b128 read.
//  - truncation hi/lo split packed with v_perm (1 inst/pair) instead of RNE
//    (~24 VALU/tile vs ~80). Error ~2^-16 rel -> absmax ~1, threshold 3.28.
//  - 3 bf16 MFMA products, fp32 acc. w[] broadcast from LDS.

typedef short short8 __attribute__((ext_vector_type(8)));   // 8 bf16 = 4 VGPRs
typedef float f32x4 __attribute__((ext_vector_type(4)));

constexpr int XD = 1024;
constexpr int KD = 64;

static __device__ __forceinline__ unsigned short f2bf(float f) {
    union { float f; unsigned u; } v; v.f = f;
    unsigned r = v.u + 0x7FFFu + ((v.u >> 16) & 1u);   // RNE
    return (unsigned short)(r >> 16);
}
static __device__ __forceinline__ float bf2f(unsigned short h) {
    union { unsigned u; float f; } v; v.u = ((unsigned)h) << 16;
    return v.f;
}
static __device__ __forceinline__ unsigned fbits(float f) {
    union { float f; unsigned u; } v; v.f = f; return v.u;
}
static __device__ __forceinline__ float bitsf(unsigned u) {
    union { unsigned u; float f; } v; v.u = u; return v.f;
}

// ---- prep: blocks 0..31 build bf16 hi/lo B-fragments (RNE); 32..35 build w ----
// B-fragment layout (mfma_f32_16x16x32_bf16): lane l holds B[k=(l>>4)*8+j][n=l&15]
// ws: bh @ 0 (131072 B) | bl @ 131072 (131072 B) | wc @ 262144 (4096 B)
__global__ void prep_kernel(const float* __restrict__ v,
                            unsigned short* __restrict__ bh,
                            unsigned short* __restrict__ bl,
                            float* __restrict__ wc) {
    if (blockIdx.x < 32) {
        int idx = blockIdx.x * 256 + threadIdx.x;
        int it = idx >> 8;
        int r  = idx & 255;
        int t  = r >> 6;
        int l  = r & 63;
        int q  = l >> 4, m = l & 15;
        int base_i = it * 32 + q * 8;
        int n = t * 16 + m;
        size_t fo = ((size_t)(it * 4 + t) * 64 + l) * 8;
#pragma unroll
        for (int j = 0; j < 8; ++j) {
            float val = v[(size_t)(base_i + j) * KD + n];
            unsigned short h = f2bf(val);
            bh[fo + j] = h;
            bl[fo + j] = f2bf(val - bf2f(h));
        }
    } else {
        int i = (blockIdx.x - 32) * 256 + threadIdx.x;   // 0..1023
        const f32x4* vp = (const f32x4*)(v + (size_t)i * KD);
        f32x4 tv[16];
#pragma unroll
        for (int qq = 0; qq < 16; ++qq) tv[qq] = vp[qq];
        float s = 0.f;
#pragma unroll
        for (int qq = 0; qq < 16; ++qq) {
            s = fmaf(tv[qq].x, tv[qq].x, s); s = fmaf(tv[qq].y, tv[qq].y, s);
            s = fmaf(tv[qq].z, tv[qq].z, s); s = fmaf(tv[qq].w, tv[qq].w, s);
        }
        wc[i] = s;
    }
}

// ---- main: 512 thr / 8 waves; block = 16 full rows; wave = 4 i-tiles ----
__global__ __launch_bounds__(512, 4)
void cross_r7(const float* __restrict__ x,
              const unsigned short* __restrict__ bh,
              const unsigned short* __restrict__ bl,
              const float* __restrict__ wc,
              float* __restrict__ out) {
    // xbuf: 16 rows x 256 float4 = 64 KB, XOR-swizzled at float4 granularity.
    // After a barrier, the front is reused as the 7-slot combine area.
    __shared__ f32x4 xb4[16 * 256];
    __shared__ float wlds[XD];         // 4 KB
    __shared__ float zb[7][16];

    const int tid = threadIdx.x;
    const int l = tid & 63;
    const int w = tid >> 6;            // wave 0..7
    const int q = l >> 4, m = l & 15;
    const int row0 = blockIdx.x * 16;

    // stage w (512 thr x float2, coalesced aligned)
    *(float2*)&wlds[tid * 2] = *(const float2*)(wc + tid * 2);

    // ---- stage x: 8 hoisted float4 loads/thread (64 KB in flight/block) ----
    f32x4 xv[8];
#pragma unroll
    for (int p = 0; p < 8; ++p) {
        int idx = p * 512 + tid;               // 0..4095 float4 slots
        int r = idx >> 8, c = idx & 255;
        xv[p] = *(const f32x4*)(x + (size_t)(row0 + r) * XD + c * 4);
    }
#pragma unroll
    for (int p = 0; p < 8; ++p) {
        int idx = p * 512 + tid;
        int r = idx >> 8, c = idx & 255;
        xb4[r * 256 + (c ^ (r & 7))] = xv[p];  // swizzled, 16B-aligned, bank-even
    }
    __syncthreads();

    // ---- compute: wave w -> i-tiles 4w .. 4w+3 ----
    f32x4 ch[4], cl1[4], cl2[4];
#pragma unroll
    for (int t = 0; t < 4; ++t) {
        ch[t]  = f32x4{0.f, 0.f, 0.f, 0.f};
        cl1[t] = f32x4{0.f, 0.f, 0.f, 0.f};
        cl2[t] = f32x4{0.f, 0.f, 0.f, 0.f};
    }
    float z = 0.f;

    const short8* bhp = (const short8*)bh;
    const short8* blp = (const short8*)bl;

#pragma unroll
    for (int ii = 0; ii < 4; ++ii) {
        const int it = w * 4 + ii;
        const size_t fbase = (size_t)(it * 4) * 64 + l;

        // x fragment: row m, float4 slots it*8+q*2, +1 (swizzled read, bank-even)
        const int c0 = it * 8 + q * 2;
        f32x4 xa = xb4[m * 256 + (c0 ^ (m & 7))];
        f32x4 xb = xb4[m * 256 + ((c0 + 1) ^ (m & 7))];

        const float* wp = &wlds[it * 32 + q * 8];
        f32x4 wa = *(const f32x4*)wp, wb = *(const f32x4*)(wp + 4);
        float xs[8] = {xa.x, xa.y, xa.z, xa.w, xb.x, xb.y, xb.z, xb.w};
        z = fmaf(xs[0]*xs[0], wa.x, z); z = fmaf(xs[1]*xs[1], wa.y, z);
        z = fmaf(xs[2]*xs[2], wa.z, z); z = fmaf(xs[3]*xs[3], wa.w, z);
        z = fmaf(xs[4]*xs[4], wb.x, z); z = fmaf(xs[5]*xs[5], wb.y, z);
        z = fmaf(xs[6]*xs[6], wb.z, z); z = fmaf(xs[7]*xs[7], wb.w, z);

        // truncation split + v_perm pack: ah = hi16 pairs, al = hi16 of (x - xh)
        unsigned ahp[4], alp[4];
#pragma unroll
        for (int jp = 0; jp < 4; ++jp) {
            unsigned u0 = fbits(xs[2 * jp]), u1 = fbits(xs[2 * jp + 1]);
            ahp[jp] = __builtin_amdgcn_perm(u1, u0, 0x07060302u);   // {hi16(u1),hi16(u0)}
            float l0 = xs[2 * jp]     - bitsf(u0 & 0xFFFF0000u);
            float l1 = xs[2 * jp + 1] - bitsf(u1 & 0xFFFF0000u);
            alp[jp] = __builtin_amdgcn_perm(fbits(l1), fbits(l0), 0x07060302u);
        }
        short8 ah, al_;
#pragma unroll
        for (int jp = 0; jp < 4; ++jp) {
            ah[2*jp]   = (short)(ahp[jp] & 0xFFFF); ah[2*jp+1]  = (short)(ahp[jp] >> 16);
            al_[2*jp]  = (short)(alp[jp] & 0xFFFF); al_[2*jp+1] = (short)(alp[jp] >> 16);
        }

#pragma unroll
        for (int t = 0; t < 4; ++t) {
            short8 vh = bhp[fbase + (size_t)t * 64];
            short8 vl = blp[fbase + (size_t)t * 64];
            ch[t]  = __builtin_amdgcn_mfma_f32_16x16x32_bf16(ah,  vh, ch[t],  0, 0, 0);
            cl1[t] = __builtin_amdgcn_mfma_f32_16x16x32_bf16(ah,  vl, cl1[t], 0, 0, 0);
            cl2[t] = __builtin_amdgcn_mfma_f32_16x16x32_bf16(al_, vh, cl2[t], 0, 0, 0);
        }
    }

    f32x4 cs[4];
#pragma unroll
    for (int t = 0; t < 4; ++t) cs[t] = ch[t] + cl1[t] + cl2[t];

    // z: sum over q-chunks -> full-q partial z for row m (this wave's i-range)
    z += __shfl_xor(z, 16);
    z += __shfl_xor(z, 32);

    __syncthreads();   // all xbuf reads done; reuse as combine area
    float* comb = (float*)xb4;   // 7 slots x 64 lanes x 17 floats = 7616 <= 16384

    if (w > 0) {
        const int s = w - 1;
#pragma unroll
        for (int t = 0; t < 4; ++t)
#pragma unroll
            for (int r = 0; r < 4; ++r) comb[(s * 64 + l) * 17 + t * 4 + r] = cs[t][r];
        if (l < 16) zb[s][l] = z;
    }
    __syncthreads();

    if (w == 0) {
#pragma unroll
        for (int s = 0; s < 7; ++s) {
#pragma unroll
            for (int t = 0; t < 4; ++t)
#pragma unroll
                for (int r = 0; r < 4; ++r) cs[t][r] += comb[(s * 64 + l) * 17 + t * 4 + r];
            z += zb[s][m];
        }

        // C layout: col = l&15, row = q*4 + reg
        float p[4] = {0.f, 0.f, 0.f, 0.f};
#pragma unroll
        for (int r = 0; r < 4; ++r)
#pragma unroll
            for (int t = 0; t < 4; ++t) p[r] = fmaf(cs[t][r], cs[t][r], p[r]);
#pragma unroll
        for (int mask = 1; mask < 16; mask <<= 1)
#pragma unroll
            for (int r = 0; r < 4; ++r) p[r] += __shfl_xor(p[r], mask);

        float zrow = __shfl(z, q * 4 + m, 16);
        if (m < 4) out[row0 + q * 4 + m] = 0.5f * (p[m] - zrow);
    }
}

extern "C" void kernel_launch(void* const* d_in, const int* in_sizes, int n_in,
                              void* d_out, int out_size, void* d_ws, size_t ws_size,
                              hipStream_t stream) {
    const float* x = (const float*)d_in[0];      // (16384, 1024) fp32
    const float* v = (const float*)d_in[1];      // (1024, 64) fp32
    float* out = (float*)d_out;                  // (16384, 1) fp32

    unsigned short* bh = (unsigned short*)d_ws;                    // 131072 B
    unsigned short* bl = (unsigned short*)((char*)d_ws + 131072);  // 131072 B
    float* wc = (float*)((char*)d_ws + 262144);                    //   4096 B

    const int B = in_sizes[0] / XD;              // 16384

    hipLaunchKernelGGL(prep_kernel, dim3(36), dim3(256), 0, stream, v, bh, bl, wc);
    hipLaunchKernelGGL(cross_r7, dim3(B / 16), dim3(512), 0, stream,
                       x, bh, bl, wc, out);
}